// Round 1
// baseline (962.300 us; speedup 1.0000x reference)
//
#include <hip/hip_runtime.h>
#include <hip/hip_bf16.h>

// Problem constants
#define BSZ 256   // batch
#define TT  512   // timesteps
#define II  512   // input dim
#define HH  1024  // hidden
#define OO  128   // output
#define BH  262144  // BSZ*HH

typedef short bfrag8 __attribute__((ext_vector_type(8)));
typedef float f32x4  __attribute__((ext_vector_type(4)));

__device__ __forceinline__ unsigned short f2bf(float f) {
    union { float f; unsigned int u; } c; c.f = f;
    unsigned int u = c.u;
    unsigned int r = u + 0x7fffu + ((u >> 16) & 1u);  // RNE
    return (unsigned short)(r >> 16);
}
__device__ __forceinline__ float bf2f(unsigned short h) {
    union { unsigned int u; float f; } c; c.u = ((unsigned int)h) << 16;
    return c.f;
}

// Split a float pair into packed bf16 hi / bf16 lo ints (v_cvt_pk_bf16_f32 path).
// Bit-identical to the previously verified split2().
__device__ __forceinline__ void pack2(float f0, float f1, int& hi, int& lo) {
    __hip_bfloat162 h2 = __float22bfloat162_rn(make_float2(f0, f1));
    float r0 = f0 - __bfloat162float(h2.x);
    float r1 = f1 - __bfloat162float(h2.y);
    __hip_bfloat162 l2 = __float22bfloat162_rn(make_float2(r0, r1));
    union { __hip_bfloat162 b; int i; } ch, cl;
    ch.b = h2; cl.b = l2;
    hi = ch.i; lo = cl.i;
}

// 8 fp32 (K-contiguous) -> hi/lo bf16 fragments
__device__ __forceinline__ void split8(f32x4 a, f32x4 b, bfrag8& hi, bfrag8& lo) {
    union { bfrag8 v; int i[4]; } H, L;
    pack2(a.x, a.y, H.i[0], L.i[0]);
    pack2(a.z, a.w, H.i[1], L.i[1]);
    pack2(b.x, b.y, H.i[2], L.i[2]);
    pack2(b.z, b.w, H.i[3], L.i[3]);
    hi = H.v; lo = L.v;
}

// ---------------------------------------------------------------------------
// Fused setup: split W_branch (NB,I,HB) fp32 -> W_hiT/W_loT [h][i] bf16, and
// init scan state (ws is poisoned each call).  (unchanged)
// ---------------------------------------------------------------------------
__global__ __launch_bounds__(256) void setup_k(const float* __restrict__ Wb,
                                               const float* __restrict__ v0,
                                               unsigned short* __restrict__ Whi,
                                               unsigned short* __restrict__ Wlo,
                                               float* __restrict__ dS, float* __restrict__ vS,
                                               float* __restrict__ sS, float* __restrict__ aS) {
    int idx = blockIdx.x * 256 + threadIdx.x;      // 0..524287  (NB*I*HB)
    int n = idx >> 17;                              // I*HB = 131072
    int rem = idx & 131071;
    int i = rem >> 8;                               // HB = 256
    int o = rem & 255;
    int h = (n << 8) + o;
    float w = Wb[idx];
    unsigned short hi = f2bf(w);
    float fh = bf2f(hi);
    unsigned short lo = f2bf(w - fh);
    Whi[(size_t)h * II + i] = hi;
    Wlo[(size_t)h * II + i] = lo;
    if (idx < BH) {
        dS[idx] = 0.0f; vS[idx] = v0[idx]; sS[idx] = 0.0f; aS[idx] = 0.0f;
    }
}

// ---------------------------------------------------------------------------
// gemm8: 256x256x(BK=32), 8 waves (2m x 4n), double-buffered 128 KiB LDS,
// 4-phase schedule per K-tile with counted vmcnt (stages issued 3 phases
// before their wait), global_load_lds staging, XOR-swizzled LDS slots,
// raw s_barrier + setprio around MFMA clusters.
//
// A is staged as RAW fp32 (pure async copy); the fp32->bf16 hi/lo split runs
// at fragment-load time on the VALU pipe (hides under MFMA). B = Whi/Wlo copy.
// LDS rows are 128 B: A[r]{32 fp32}, B[n]{32 hi shorts | 32 lo shorts}.
// Swizzle: 16B-slot s of row r lives at slot s^(r&7)  (both-sides involution:
// pre-swizzled global source for the DMA, swizzled offsets on ds_read).
//
// Numerics: identical inputs / split math / MFMA order (hh,hl,lh) / k order
// as the verified kernel => bit-identical U.
// ---------------------------------------------------------------------------
#define GLL16(G, Lp) __builtin_amdgcn_global_load_lds(                         \
    (const __attribute__((address_space(1))) void*)(G),                        \
    (__attribute__((address_space(3))) void*)(Lp), 16, 0, 0)

#define BAR() do { asm volatile("" ::: "memory");                              \
                   __builtin_amdgcn_s_barrier();                               \
                   asm volatile("" ::: "memory"); } while (0)

// 8 global_load_lds per wave per K-tile (4 A + 4 B), 16 B each, lane-linear
// LDS dest, inverse-swizzled per-lane global source.
#define STAGE(K0, BUFB) do {                                                   \
    _Pragma("unroll") for (int j_ = 0; j_ < 4; ++j_) {                         \
        int w8_ = (j_ << 3) + wv;                                              \
        GLL16(gA + (K0) + ((size_t)w8_ << 12), smem + (BUFB) + (w8_ << 10));   \
        GLL16(gB + (K0) + ((size_t)w8_ << 12), smem + (BUFB) + 32768 + (w8_ << 10)); \
    } } while (0)

// Load 2 A m-frags (F, F+1) from buffer BUFB, split fp32 -> hi/lo bf16 frags.
#define LOADA2(F, BUFB, H0, L0, H1, L1) do {                                   \
    const char* p_ = smem + (BUFB) + aRow + ((F) << 11);                       \
    f32x4 x0_ = *(const f32x4*)(p_ + aO0);                                     \
    f32x4 x1_ = *(const f32x4*)(p_ + aO1);                                     \
    f32x4 x2_ = *(const f32x4*)(p_ + 2048 + aO0);                              \
    f32x4 x3_ = *(const f32x4*)(p_ + 2048 + aO1);                              \
    split8(x0_, x1_, H0, L0);                                                  \
    split8(x2_, x3_, H1, L1);                                                  \
} while (0)

// Load all 4 B n-frags (hi+lo) of this tile.
#define LOADB(BUFB) do {                                                       \
    const char* p_ = smem + (BUFB) + bRow;                                     \
    _Pragma("unroll") for (int g_ = 0; g_ < 4; ++g_) {                         \
        bh[g_] = *(const bfrag8*)(p_ + (g_ << 11) + bO0);                      \
        bl[g_] = *(const bfrag8*)(p_ + (g_ << 11) + bO1);                      \
    } } while (0)

#define MFMA3(AH, AL, BHG, BLG, C) do {                                        \
    C = __builtin_amdgcn_mfma_f32_16x16x32_bf16(AH, BHG, C, 0, 0, 0);          \
    C = __builtin_amdgcn_mfma_f32_16x16x32_bf16(AH, BLG, C, 0, 0, 0);          \
    C = __builtin_amdgcn_mfma_f32_16x16x32_bf16(AL, BHG, C, 0, 0, 0);          \
} while (0)

// One phase's MFMA cluster: 2 m-frags x 4 n-frags x 3 products = 24 MFMA.
#define MM2(F, H0, L0, H1, L1) do {                                            \
    __builtin_amdgcn_s_setprio(1);                                             \
    _Pragma("unroll") for (int g_ = 0; g_ < 4; ++g_) {                         \
        MFMA3(H0, L0, bh[g_], bl[g_], acc[F][g_]);                             \
        MFMA3(H1, L1, bh[g_], bl[g_], acc[(F) + 1][g_]);                       \
    }                                                                          \
    __builtin_amdgcn_s_setprio(0);                                             \
} while (0)

__global__ __launch_bounds__(512, 2) void gemm8(const float* __restrict__ X,
    const unsigned short* __restrict__ Whi, const unsigned short* __restrict__ Wlo,
    float* __restrict__ U)
{
    extern __shared__ char smem[];   // 2 x { A: 32 KiB fp32 | B: 32 KiB bf16 hi/lo }

    // bijective XCD-chunked swizzle (2048 % 8 == 0): each XCD gets a
    // contiguous run of logical blocks; n fastest so the 4 blocks sharing an
    // A-panel are adjacent (L2 reuse; 8 live panels/XCD = 4 MiB = L2).
    const int P = blockIdx.x;
    const int L = ((P & 7) << 8) | (P >> 3);
    const int m0 = (L >> 2) << 8;          // 512 m-tiles of 256 (m = b*512 + t)
    const int h0 = (L & 3) << 8;           // 4 n-tiles of 256

    const int tid = threadIdx.x;
    const int lane = tid & 63;
    const int wv = tid >> 6;               // 0..7
    const int l16 = lane & 15;
    const int q = lane >> 4;               // 0..3
    const int wm = wv >> 2, wn = wv & 3;   // wave -> (128-row, 64-col) subtile

    // swizzled read offsets (constant per lane)
    const int e = l16 & 7;
    const int aRow = ((wm << 7) + l16) << 7;            // byte
    const int aO0 = ((((q << 1)    ) ^ e) << 4);
    const int aO1 = ((((q << 1) | 1) ^ e) << 4);
    const int bRow = (((wn << 6) + l16) << 7) + 32768;  // byte (B part)
    const int bO0 = (((q    ) ^ e) << 4);
    const int bO1 = (((q + 4) ^ e) << 4);

    // staging source (constant per lane): inverse-swizzled slot
    const int rl = lane >> 3;                       // row within 8-row group
    const int sp = (lane & 7) ^ (rl & 7);           // unswizzled 16B slot
    const float* gA = X + ((size_t)(m0 + rl) << 9) + (sp << 2);
    const unsigned short* gB = (sp < 4)
        ? (Whi + ((size_t)(h0 + rl) << 9) + (sp << 3))
        : (Wlo + ((size_t)(h0 + rl) << 9) + ((sp - 4) << 3));

    f32x4 acc[8][4];
#pragma unroll
    for (int i = 0; i < 8; ++i)
#pragma unroll
        for (int j = 0; j < 4; ++j)
#pragma unroll
            for (int r = 0; r < 4; ++r) acc[i][j][r] = 0.0f;

    bfrag8 a0h, a0l, a1h, a1l;   // A frag set (even phases)
    bfrag8 b0h, b0l, b1h, b1l;   // A frag set (odd phases)
    bfrag8 bh[4], bl[4];         // B frags of current tile

    // prologue: stage tiles 0,1; counted wait leaves tile-1's 8 loads in flight
    STAGE(0, 0);
    STAGE(32, 65536);
    asm volatile("s_waitcnt vmcnt(8)" ::: "memory");
    __builtin_amdgcn_s_barrier();
    asm volatile("" ::: "memory");
    LOADA2(0, 0, a0h, a0l, a1h, a1l);

    // 16 K-tiles, 2 per iteration. Per tile, 4 phases; stages for tile t+2
    // issue at P3 of tile t and are waited at P2 of tile t+1 (3-phase lead).
    // lgkmcnt(0) before the P2 barrier closes the ds_read-in-flight vs
    // DMA-overwrite hazard of the following STAGE.
#pragma unroll 1
    for (int tt = 0; tt < 16; tt += 2) {
        const int k2 = (tt << 5) + 64;   // k0 of tile tt+2
        // ---------------- even tile (buf 0) ----------------
        LOADB(0);
        LOADA2(2, 0, b0h, b0l, b1h, b1l);
        MM2(0, a0h, a0l, a1h, a1l);
        BAR();
        LOADA2(4, 0, a0h, a0l, a1h, a1l);
        MM2(2, b0h, b0l, b1h, b1l);
        BAR();
        LOADA2(6, 0, b0h, b0l, b1h, b1l);
        MM2(4, a0h, a0l, a1h, a1l);
        asm volatile("s_waitcnt vmcnt(0) lgkmcnt(0)" ::: "memory");
        BAR();
        if (tt < 14) STAGE(k2, 0);                    // tile tt+2 -> buf0
        LOADA2(0, 65536, a0h, a0l, a1h, a1l);         // tile tt+1 frags {0,1}
        MM2(6, b0h, b0l, b1h, b1l);
        BAR();
        // ---------------- odd tile (buf 1) ----------------
        LOADB(65536);
        LOADA2(2, 65536, b0h, b0l, b1h, b1l);
        MM2(0, a0h, a0l, a1h, a1l);
        BAR();
        LOADA2(4, 65536, a0h, a0l, a1h, a1l);
        MM2(2, b0h, b0l, b1h, b1l);
        BAR();
        LOADA2(6, 65536, b0h, b0l, b1h, b1l);
        MM2(4, a0h, a0l, a1h, a1l);
        asm volatile("s_waitcnt vmcnt(0) lgkmcnt(0)" ::: "memory");
        BAR();
        if (tt < 13) STAGE(k2 + 32, 65536);           // tile tt+3 -> buf1
        if (tt < 14) LOADA2(0, 0, a0h, a0l, a1h, a1l);// tile tt+2 frags {0,1}
        MM2(6, b0h, b0l, b1h, b1l);
        BAR();
    }

    // epilogue: C/D layout col = lane&15, row = (lane>>4)*4 + rr
    // U layout [t][b][h] (t-major for scan); m = b*512 + t.
#pragma unroll
    for (int f = 0; f < 8; ++f) {
        const int rb = m0 + (wm << 7) + (f << 4) + (q << 2);
#pragma unroll
        for (int rr = 0; rr < 4; ++rr) {
            const int m = rb + rr;
            const size_t base =
                (((size_t)((m & 511) << 8) + (m >> 9)) << 10) + h0 + (wn << 6) + l16;
#pragma unroll
            for (int g = 0; g < 4; ++g) U[base + (g << 4)] = acc[f][g][rr];
        }
    }
}

// ---------------------------------------------------------------------------
// Scan: one thread per (b,h) scalar -> 262144 threads = 1024 blocks =
// 16 waves/CU. Depth-16 register pipeline, drain tail outside the hot loop.
// (unchanged)
// ---------------------------------------------------------------------------
__global__ __launch_bounds__(256) void scan_chunk(const float* __restrict__ U,
    const float* __restrict__ tau_n, const float* __restrict__ tau_m,
    float* __restrict__ dS, float* __restrict__ vS,
    float* __restrict__ sS, float* __restrict__ aS, int t0, int Tc)
{
    int idx = blockIdx.x * 256 + threadIdx.x;  // b*H + h
    int h = idx & (HH - 1);
    float beta  = 1.0f / (1.0f + __expf(-tau_n[h]));
    float alpha = 1.0f / (1.0f + __expf(-tau_m[h]));
    float ob = 1.0f - beta, oa = 1.0f - alpha;
    float dd = dS[idx], vv = vS[idx], ss = sS[idx], aa = aS[idx];
    const float* Up = U + idx;   // per-t stride = BH floats

    float u[16];
#pragma unroll
    for (int j = 0; j < 16; ++j) u[j] = Up[(size_t)j << 18];

    int tg = 0;
    for (; tg + 16 < Tc; tg += 16) {
#pragma unroll
        for (int j = 0; j < 16; ++j) {
            float uu = u[j];
            u[j] = Up[(size_t)(tg + 16 + j) << 18];
            float msk = ((t0 + tg + j) >= (TT / 2)) ? 1.0f : 0.0f;
            dd = beta * dd + ob * uu;
            vv = alpha * vv + oa * dd - ss;   // prev s; V_TH=1
            ss = (vv > 1.0f) ? 1.0f : 0.0f;
            aa += msk * ss;
        }
    }
#pragma unroll
    for (int j = 0; j < 16; ++j) {           // drain
        float uu = u[j];
        float msk = ((t0 + tg + j) >= (TT / 2)) ? 1.0f : 0.0f;
        dd = beta * dd + ob * uu;
        vv = alpha * vv + oa * dd - ss;
        ss = (vv > 1.0f) ? 1.0f : 0.0f;
        aa += msk * ss;
    }
    dS[idx] = dd; vS[idx] = vv; sS[idx] = ss; aS[idx] = aa;
}

// ---------------------------------------------------------------------------
// out[b][o] = sum_h acc[b][h] * W_out[h][o] + b_out[o]   (unchanged)
// ---------------------------------------------------------------------------
__global__ __launch_bounds__(256) void out_gemm(const float* __restrict__ acc,
    const float* __restrict__ Wout, const float* __restrict__ bout,
    float* __restrict__ out)
{
    __shared__ float a_s[HH];
    __shared__ float partial[OO];
    int b = blockIdx.x;
    int o = threadIdx.x & (OO - 1);
    int half = threadIdx.x >> 7;
    for (int i = threadIdx.x; i < HH; i += 256) a_s[i] = acc[b * HH + i];
    __syncthreads();
    float sum = half ? 0.0f : bout[o];
    const float* Wp = Wout + (size_t)half * 512 * OO + o;
    const float* ap = a_s + half * 512;
#pragma unroll 8
    for (int h = 0; h < 512; ++h) sum = fmaf(ap[h], Wp[(size_t)h * OO], sum);
    if (half) partial[o] = sum;
    __syncthreads();
    if (!half) out[b * OO + o] = sum + partial[o];
}

// ---------------------------------------------------------------------------
extern "C" void kernel_launch(void* const* d_in, const int* in_sizes, int n_in,
                              void* d_out, int out_size, void* d_ws, size_t ws_size,
                              hipStream_t stream) {
    const float* x     = (const float*)d_in[0];
    const float* v0    = (const float*)d_in[1];
    const float* Wb    = (const float*)d_in[2];
    const float* tau_n = (const float*)d_in[3];
    const float* tau_m = (const float*)d_in[4];
    const float* Wout  = (const float*)d_in[5];
    const float* bout  = (const float*)d_in[6];
    float* out = (float*)d_out;

    // workspace layout (1 MiB units); U = 512 MiB (full-T chunk: proven to
    // fit on this harness — previous runs dispatched a single full gemm).
    char* ws = (char*)d_ws;
    unsigned short* Whi = (unsigned short*)(ws);                 // 1 MiB
    unsigned short* Wlo = (unsigned short*)(ws + (1ll << 20));   // 1 MiB
    float* dS = (float*)(ws + (2ll << 20));
    float* vS = (float*)(ws + (3ll << 20));
    float* sS = (float*)(ws + (4ll << 20));
    float* aS = (float*)(ws + (5ll << 20));
    float* U  = (float*)(ws + (6ll << 20));

    // 128 KiB dynamic LDS (> 64 KiB default cap)
    hipFuncSetAttribute((const void*)gemm8,
                        hipFuncAttributeMaxDynamicSharedMemorySize, 131072);

    setup_k<<<2048, 256, 0, stream>>>(Wb, v0, Whi, Wlo, dS, vS, sS, aS);
    gemm8<<<2048, 512, 131072, stream>>>(x, Whi, Wlo, U);
    scan_chunk<<<BH / 256, 256, 0, stream>>>(U, tau_n, tau_m, dS, vS, sS, aS, 0, TT);
    out_gemm<<<BSZ, 256, 0, stream>>>(aS, Wout, bout, out);
}

// Round 2
// 936.916 us; speedup vs baseline: 1.0271x; 1.0271x over previous
//
#include <hip/hip_runtime.h>
#include <hip/hip_bf16.h>

// Problem constants
#define BSZ 256   // batch
#define TT  512   // timesteps
#define II  512   // input dim
#define HH  1024  // hidden
#define OO  128   // output
#define BH  262144  // BSZ*HH
#define TC  256   // T-chunk (keeps ws at proven 518 MiB; 256-m tiles stay row-contiguous)

typedef short bfrag8 __attribute__((ext_vector_type(8)));
typedef float f32x4  __attribute__((ext_vector_type(4)));

__device__ __forceinline__ unsigned short f2bf(float f) {
    union { float f; unsigned int u; } c; c.f = f;
    unsigned int u = c.u;
    unsigned int r = u + 0x7fffu + ((u >> 16) & 1u);  // RNE
    return (unsigned short)(r >> 16);
}
__device__ __forceinline__ float bf2f(unsigned short h) {
    union { unsigned int u; float f; } c; c.u = ((unsigned int)h) << 16;
    return c.f;
}

// float pair -> packed bf16 hi / bf16 lo ints (bit-identical to verified split2)
__device__ __forceinline__ void pack2(float f0, float f1, int& hi, int& lo) {
    __hip_bfloat162 h2 = __float22bfloat162_rn(make_float2(f0, f1));
    float r0 = f0 - __bfloat162float(h2.x);
    float r1 = f1 - __bfloat162float(h2.y);
    __hip_bfloat162 l2 = __float22bfloat162_rn(make_float2(r0, r1));
    union { __hip_bfloat162 b; int i; } ch, cl;
    ch.b = h2; cl.b = l2;
    hi = ch.i; lo = cl.i;
}

// ---------------------------------------------------------------------------
// setup_k: split W_branch (NB,I,HB) fp32 -> W_hiT/W_loT [h][i] bf16, and
// init scan state.  (unchanged, verified)
// ---------------------------------------------------------------------------
__global__ __launch_bounds__(256) void setup_k(const float* __restrict__ Wb,
                                               const float* __restrict__ v0,
                                               unsigned short* __restrict__ Whi,
                                               unsigned short* __restrict__ Wlo,
                                               float* __restrict__ dS, float* __restrict__ vS,
                                               float* __restrict__ sS, float* __restrict__ aS) {
    int idx = blockIdx.x * 256 + threadIdx.x;      // 0..524287  (NB*I*HB)
    int n = idx >> 17;                              // I*HB = 131072
    int rem = idx & 131071;
    int i = rem >> 8;                               // HB = 256
    int o = rem & 255;
    int h = (n << 8) + o;
    float w = Wb[idx];
    unsigned short hi = f2bf(w);
    float fh = bf2f(hi);
    unsigned short lo = f2bf(w - fh);
    Whi[(size_t)h * II + i] = hi;
    Wlo[(size_t)h * II + i] = lo;
    if (idx < BH) {
        dS[idx] = 0.0f; vS[idx] = v0[idx]; sS[idx] = 0.0f; aS[idx] = 0.0f;
    }
}

// ---------------------------------------------------------------------------
// split_x: X fp32 [m][512] -> Xhi/Xlo bf16 [m][512] (m = b*512+t). Pure
// streaming pass; moves the hi/lo split out of the gemm inner loop so gemm
// staging is pure global_load_lds DMA. Same split bits as in-gemm split.
// ---------------------------------------------------------------------------
__global__ __launch_bounds__(256) void split_x(const float* __restrict__ X,
    unsigned short* __restrict__ Xhi, unsigned short* __restrict__ Xlo)
{
    size_t idx = ((size_t)blockIdx.x * 256 + threadIdx.x) << 3;   // 8 floats
    f32x4 v0 = *(const f32x4*)(X + idx);
    f32x4 v1 = *(const f32x4*)(X + idx + 4);
    union { uint4 v; int i[4]; } H, L;
    pack2(v0.x, v0.y, H.i[0], L.i[0]);
    pack2(v0.z, v0.w, H.i[1], L.i[1]);
    pack2(v1.x, v1.y, H.i[2], L.i[2]);
    pack2(v1.z, v1.w, H.i[3], L.i[3]);
    *(uint4*)(Xhi + idx) = H.v;
    *(uint4*)(Xlo + idx) = L.v;
}

// ---------------------------------------------------------------------------
// gemm8: 256x256x(BK=32), 8 waves (2m x 4n), double-buffered 128 KiB LDS.
// Both A and B staged as pre-split bf16 [hi 64B | lo 64B] 128-B LDS rows via
// global_load_lds (pure DMA, zero in-loop VALU conversion). XOR slot swizzle
// (slot^row&7) on both DMA source and ds_read (proven B-path, now A too).
// 4 phases/K-tile; counted vmcnt(8): tile t+2's loads stay in flight across
// the tile boundary (T4); single vmcnt(0) only at tile 14.
// Numerics: identical split bits / MFMA order (hh,hl,lh) / k order as the
// verified kernel => bit-identical U.
// ---------------------------------------------------------------------------
#define GLL16(G, Lp) __builtin_amdgcn_global_load_lds(                         \
    (const __attribute__((address_space(1))) void*)(G),                        \
    (__attribute__((address_space(3))) void*)(Lp), 16, 0, 0)

#define BAR() do { asm volatile("" ::: "memory");                              \
                   __builtin_amdgcn_s_barrier();                               \
                   asm volatile("" ::: "memory"); } while (0)

// 8 global_load_lds per wave per K-tile (4 A + 4 B), 16 B/lane, lane-linear
// LDS dest, inverse-swizzled per-lane global source. K0 in elements (ushort).
#define STAGE(K0, BUFB) do {                                                   \
    _Pragma("unroll") for (int j_ = 0; j_ < 4; ++j_) {                         \
        int w8_ = (j_ << 3) + wv;                                              \
        GLL16(gA + (K0) + ((size_t)w8_ << 12), smem + (BUFB) + (w8_ << 10));   \
        GLL16(gB + (K0) + ((size_t)w8_ << 12), smem + (BUFB) + 32768 + (w8_ << 10)); \
    } } while (0)

// Load A m-frags F, F+1 (hi+lo) from buffer BUFB: 4 x ds_read_b128.
#define LDA2(F, BUFB, H0, L0, H1, L1) do {                                     \
    const char* p_ = smem + (BUFB) + aRow + ((F) << 11);                       \
    H0 = *(const bfrag8*)(p_ + sH);                                            \
    L0 = *(const bfrag8*)(p_ + sL);                                            \
    H1 = *(const bfrag8*)(p_ + 2048 + sH);                                     \
    L1 = *(const bfrag8*)(p_ + 2048 + sL);                                     \
} while (0)

// Load all 4 B n-frags (hi+lo) of this tile: 8 x ds_read_b128.
#define LOADB(BUFB) do {                                                       \
    const char* p_ = smem + (BUFB) + bRow;                                     \
    _Pragma("unroll") for (int g_ = 0; g_ < 4; ++g_) {                         \
        bh[g_] = *(const bfrag8*)(p_ + (g_ << 11) + sH);                       \
        bl[g_] = *(const bfrag8*)(p_ + (g_ << 11) + sL);                       \
    } } while (0)

#define MFMA3(AH, AL, BHG, BLG, C) do {                                        \
    C = __builtin_amdgcn_mfma_f32_16x16x32_bf16(AH, BHG, C, 0, 0, 0);          \
    C = __builtin_amdgcn_mfma_f32_16x16x32_bf16(AH, BLG, C, 0, 0, 0);          \
    C = __builtin_amdgcn_mfma_f32_16x16x32_bf16(AL, BHG, C, 0, 0, 0);          \
} while (0)

// One phase's MFMA cluster: 2 m-frags x 4 n-frags x 3 products = 24 MFMA.
#define MM2(F, H0, L0, H1, L1) do {                                            \
    __builtin_amdgcn_s_setprio(1);                                             \
    _Pragma("unroll") for (int g_ = 0; g_ < 4; ++g_) {                         \
        MFMA3(H0, L0, bh[g_], bl[g_], acc[F][g_]);                             \
        MFMA3(H1, L1, bh[g_], bl[g_], acc[(F) + 1][g_]);                       \
    }                                                                          \
    __builtin_amdgcn_s_setprio(0);                                             \
} while (0)

__global__ __launch_bounds__(512, 2) void gemm8(
    const unsigned short* __restrict__ Xhi, const unsigned short* __restrict__ Xlo,
    const unsigned short* __restrict__ Whi, const unsigned short* __restrict__ Wlo,
    float* __restrict__ U, int xrow0)
{
    extern __shared__ char smem[];   // 2 x { A: 32 KiB | B: 32 KiB }

    // bijective XCD-chunked swizzle (1024 % 8 == 0); n fastest (A-panel reuse).
    const int P = blockIdx.x;
    const int L = ((P & 7) << 7) | (P >> 3);
    const int m0 = (L >> 2) << 8;          // 256 m-tiles of 256 (m = b*TC + tl)
    const int h0 = (L & 3) << 8;           // 4 n-tiles of 256

    const int tid = threadIdx.x;
    const int lane = tid & 63;
    const int wv = tid >> 6;               // 0..7
    const int l16 = lane & 15;
    const int q = lane >> 4;               // 0..3
    const int wm = wv >> 2, wn = wv & 3;   // wave -> (128-row, 64-col) subtile

    // swizzled read offsets (constant per lane)
    const int e = l16 & 7;
    const int sH = ((q ^ e) << 4);          // hi 16B slot
    const int sL = (((q + 4) ^ e) << 4);    // lo 16B slot
    const int aRow = ((wm << 7) + l16) << 7;            // byte, A region
    const int bRow = (((wn << 6) + l16) << 7) + 32768;  // byte, B region

    // staging source (constant per lane): inverse-swizzled slot
    const int rl = lane >> 3;                       // row within 8-row group
    const int sp = (lane & 7) ^ rl;                 // unswizzled 16B slot
    const int grow0 = (m0 << 1) + xrow0;            // global X row of tile row 0
    const unsigned short* gA = (sp < 4)
        ? (Xhi + ((size_t)(grow0 + rl) << 9) + (sp << 3))
        : (Xlo + ((size_t)(grow0 + rl) << 9) + ((sp - 4) << 3));
    const unsigned short* gB = (sp < 4)
        ? (Whi + ((size_t)(h0 + rl) << 9) + (sp << 3))
        : (Wlo + ((size_t)(h0 + rl) << 9) + ((sp - 4) << 3));

    f32x4 acc[8][4];
#pragma unroll
    for (int i = 0; i < 8; ++i)
#pragma unroll
        for (int j = 0; j < 4; ++j)
#pragma unroll
            for (int r = 0; r < 4; ++r) acc[i][j][r] = 0.0f;

    bfrag8 a0h, a0l, a1h, a1l;   // A frag set (even phases)
    bfrag8 b0h, b0l, b1h, b1l;   // A frag set (odd phases)
    bfrag8 bh[4], bl[4];         // B frags of current tile

    // prologue: stage tiles 0,1; counted wait leaves tile-1's 8 loads in flight
    STAGE(0, 0);
    STAGE(32, 65536);
    asm volatile("s_waitcnt vmcnt(8)" ::: "memory");
    __builtin_amdgcn_s_barrier();
    asm volatile("" ::: "memory");
    LDA2(0, 0, a0h, a0l, a1h, a1l);

    // 16 K-tiles, 2 per iteration (even=buf0, odd=buf1). Per tile 4 phases:
    //  P1: LOADB + LDA2(2,3) + MFMA(0,1)
    //  P2: LDA2(4,5) + MFMA(2,3)
    //  P3: LDA2(6,7) + MFMA(4,5) + lgkmcnt(0)   (closes read-vs-DMA hazard)
    //  P4: STAGE(t+2) + MFMA(6,7) + vmcnt(8) + LDA2(t+1 frags 0,1)
#pragma unroll 1
    for (int tt = 0; tt < 16; tt += 2) {
        const int k2 = (tt << 5) + 64;   // k0 of tile tt+2 (elements)
        // ---------------- even tile (buf 0) ----------------
        LOADB(0);
        LDA2(2, 0, b0h, b0l, b1h, b1l);
        MM2(0, a0h, a0l, a1h, a1l);
        BAR();
        LDA2(4, 0, a0h, a0l, a1h, a1l);
        MM2(2, b0h, b0l, b1h, b1l);
        BAR();
        LDA2(6, 0, b0h, b0l, b1h, b1l);
        MM2(4, a0h, a0l, a1h, a1l);
        asm volatile("s_waitcnt lgkmcnt(0)" ::: "memory");
        BAR();
        if (tt < 14) {
            STAGE(k2, 0);                             // tile tt+2 -> buf0
            MM2(6, b0h, b0l, b1h, b1l);
            asm volatile("s_waitcnt vmcnt(8)" ::: "memory");   // tt+1 staged
        } else {
            MM2(6, b0h, b0l, b1h, b1l);
            asm volatile("s_waitcnt vmcnt(0)" ::: "memory");   // tile 15 staged
        }
        LDA2(0, 65536, a0h, a0l, a1h, a1l);           // tile tt+1 frags {0,1}
        BAR();
        // ---------------- odd tile (buf 1) ----------------
        LOADB(65536);
        LDA2(2, 65536, b0h, b0l, b1h, b1l);
        MM2(0, a0h, a0l, a1h, a1l);
        BAR();
        LDA2(4, 65536, a0h, a0l, a1h, a1l);
        MM2(2, b0h, b0l, b1h, b1l);
        BAR();
        LDA2(6, 65536, b0h, b0l, b1h, b1l);
        MM2(4, a0h, a0l, a1h, a1l);
        asm volatile("s_waitcnt lgkmcnt(0)" ::: "memory");
        BAR();
        if (tt < 13) {
            STAGE(k2 + 32, 65536);                    // tile tt+3 -> buf1
            MM2(6, b0h, b0l, b1h, b1l);
            asm volatile("s_waitcnt vmcnt(8)" ::: "memory");   // tt+2 staged
            LDA2(0, 0, a0h, a0l, a1h, a1l);           // tile tt+2 frags {0,1}
        } else {
            MM2(6, b0h, b0l, b1h, b1l);               // tile 15: done
        }
        BAR();
    }

    // epilogue: C/D layout col = lane&15, row = (lane>>4)*4 + rr
    // U layout [tl][b][h] (tl local to chunk); m = b*TC + tl.
#pragma unroll
    for (int f = 0; f < 8; ++f) {
        const int rb = m0 + (wm << 7) + (f << 4) + (q << 2);
#pragma unroll
        for (int rr = 0; rr < 4; ++rr) {
            const int m = rb + rr;
            const size_t base =
                (((size_t)((m & 255) << 8) + (m >> 8)) << 10) + h0 + (wn << 6) + l16;
#pragma unroll
            for (int g = 0; g < 4; ++g) U[base + (g << 4)] = acc[f][g][rr];
        }
    }
}

// ---------------------------------------------------------------------------
// Scan: one thread per (b,h) scalar; depth-16 register pipeline. (unchanged)
// ---------------------------------------------------------------------------
__global__ __launch_bounds__(256) void scan_chunk(const float* __restrict__ U,
    const float* __restrict__ tau_n, const float* __restrict__ tau_m,
    float* __restrict__ dS, float* __restrict__ vS,
    float* __restrict__ sS, float* __restrict__ aS, int t0, int Tc)
{
    int idx = blockIdx.x * 256 + threadIdx.x;  // b*H + h
    int h = idx & (HH - 1);
    float beta  = 1.0f / (1.0f + __expf(-tau_n[h]));
    float alpha = 1.0f / (1.0f + __expf(-tau_m[h]));
    float ob = 1.0f - beta, oa = 1.0f - alpha;
    float dd = dS[idx], vv = vS[idx], ss = sS[idx], aa = aS[idx];
    const float* Up = U + idx;   // per-t stride = BH floats

    float u[16];
#pragma unroll
    for (int j = 0; j < 16; ++j) u[j] = Up[(size_t)j << 18];

    int tg = 0;
    for (; tg + 16 < Tc; tg += 16) {
#pragma unroll
        for (int j = 0; j < 16; ++j) {
            float uu = u[j];
            u[j] = Up[(size_t)(tg + 16 + j) << 18];
            float msk = ((t0 + tg + j) >= (TT / 2)) ? 1.0f : 0.0f;
            dd = beta * dd + ob * uu;
            vv = alpha * vv + oa * dd - ss;   // prev s; V_TH=1
            ss = (vv > 1.0f) ? 1.0f : 0.0f;
            aa += msk * ss;
        }
    }
#pragma unroll
    for (int j = 0; j < 16; ++j) {           // drain
        float uu = u[j];
        float msk = ((t0 + tg + j) >= (TT / 2)) ? 1.0f : 0.0f;
        dd = beta * dd + ob * uu;
        vv = alpha * vv + oa * dd - ss;
        ss = (vv > 1.0f) ? 1.0f : 0.0f;
        aa += msk * ss;
    }
    dS[idx] = dd; vS[idx] = vv; sS[idx] = ss; aS[idx] = aa;
}

// ---------------------------------------------------------------------------
// out[b][o] = sum_h acc[b][h] * W_out[h][o] + b_out[o]   (unchanged)
// ---------------------------------------------------------------------------
__global__ __launch_bounds__(256) void out_gemm(const float* __restrict__ acc,
    const float* __restrict__ Wout, const float* __restrict__ bout,
    float* __restrict__ out)
{
    __shared__ float a_s[HH];
    __shared__ float partial[OO];
    int b = blockIdx.x;
    int o = threadIdx.x & (OO - 1);
    int half = threadIdx.x >> 7;
    for (int i = threadIdx.x; i < HH; i += 256) a_s[i] = acc[b * HH + i];
    __syncthreads();
    float sum = half ? 0.0f : bout[o];
    const float* Wp = Wout + (size_t)half * 512 * OO + o;
    const float* ap = a_s + half * 512;
#pragma unroll 8
    for (int h = 0; h < 512; ++h) sum = fmaf(ap[h], Wp[(size_t)h * OO], sum);
    if (half) partial[o] = sum;
    __syncthreads();
    if (!half) out[b * OO + o] = sum + partial[o];
}

// ---------------------------------------------------------------------------
extern "C" void kernel_launch(void* const* d_in, const int* in_sizes, int n_in,
                              void* d_out, int out_size, void* d_ws, size_t ws_size,
                              hipStream_t stream) {
    const float* x     = (const float*)d_in[0];
    const float* v0    = (const float*)d_in[1];
    const float* Wb    = (const float*)d_in[2];
    const float* tau_n = (const float*)d_in[3];
    const float* tau_m = (const float*)d_in[4];
    const float* Wout  = (const float*)d_in[5];
    const float* bout  = (const float*)d_in[6];
    float* out = (float*)d_out;

    // workspace layout (total 518 MiB == proven footprint):
    //  Whi 1M | Wlo 1M | dS 1M | vS 1M | sS 1M | aS 1M | Xhi 128M | Xlo 128M | U 256M
    char* ws = (char*)d_ws;
    unsigned short* Whi = (unsigned short*)(ws);
    unsigned short* Wlo = (unsigned short*)(ws + (1ll << 20));
    float* dS = (float*)(ws + (2ll << 20));
    float* vS = (float*)(ws + (3ll << 20));
    float* sS = (float*)(ws + (4ll << 20));
    float* aS = (float*)(ws + (5ll << 20));
    unsigned short* Xhi = (unsigned short*)(ws + (6ll << 20));
    unsigned short* Xlo = (unsigned short*)(ws + (134ll << 20));
    float* U  = (float*)(ws + (262ll << 20));

    // 128 KiB dynamic LDS (> 64 KiB default cap)
    hipFuncSetAttribute((const void*)gemm8,
                        hipFuncAttributeMaxDynamicSharedMemorySize, 131072);

    setup_k<<<2048, 256, 0, stream>>>(Wb, v0, Whi, Wlo, dS, vS, sS, aS);
    split_x<<<32768, 256, 0, stream>>>(x, Xhi, Xlo);

    for (int t0 = 0; t0 < TT; t0 += TC) {
        gemm8<<<1024, 512, 131072, stream>>>(Xhi, Xlo, Whi, Wlo, U, t0);
        scan_chunk<<<BH / 256, 256, 0, stream>>>(U, tau_n, tau_m, dS, vS, sS, aS, t0, TC);
    }
    out_gemm<<<BSZ, 256, 0, stream>>>(aS, Wout, bout, out);
}

// Round 5
// 818.907 us; speedup vs baseline: 1.1751x; 1.1441x over previous
//
#include <hip/hip_runtime.h>
#include <hip/hip_bf16.h>

// Problem constants
#define BSZ 256   // batch
#define TT  512   // timesteps
#define II  512   // input dim
#define HH  1024  // hidden
#define OO  128   // output
#define BH  262144  // BSZ*HH
#define TC  256   // T-chunk: one gemm block owns (batch b, h-panel) x ALL tl -> scan fuses in

typedef short bfrag8 __attribute__((ext_vector_type(8)));
typedef float f32x4  __attribute__((ext_vector_type(4)));

__device__ __forceinline__ unsigned short f2bf(float f) {
    union { float f; unsigned int u; } c; c.f = f;
    unsigned int u = c.u;
    unsigned int r = u + 0x7fffu + ((u >> 16) & 1u);  // RNE
    return (unsigned short)(r >> 16);
}
__device__ __forceinline__ float bf2f(unsigned short h) {
    union { unsigned int u; float f; } c; c.u = ((unsigned int)h) << 16;
    return c.f;
}

// float pair -> packed bf16 hi / bf16 lo ints (bit-identical to verified split2)
__device__ __forceinline__ void pack2(float f0, float f1, int& hi, int& lo) {
    __hip_bfloat162 h2 = __float22bfloat162_rn(make_float2(f0, f1));
    float r0 = f0 - __bfloat162float(h2.x);
    float r1 = f1 - __bfloat162float(h2.y);
    __hip_bfloat162 l2 = __float22bfloat162_rn(make_float2(r0, r1));
    union { __hip_bfloat162 b; int i; } ch, cl;
    ch.b = h2; cl.b = l2;
    hi = ch.i; lo = cl.i;
}

// ---------------------------------------------------------------------------
// setup_k: split W_branch (NB,I,HB) fp32 -> W_hiT/W_loT [h][i] bf16, and
// init scan state.  (unchanged, verified)
// ---------------------------------------------------------------------------
__global__ __launch_bounds__(256) void setup_k(const float* __restrict__ Wb,
                                               const float* __restrict__ v0,
                                               unsigned short* __restrict__ Whi,
                                               unsigned short* __restrict__ Wlo,
                                               float* __restrict__ dS, float* __restrict__ vS,
                                               float* __restrict__ sS, float* __restrict__ aS) {
    int idx = blockIdx.x * 256 + threadIdx.x;      // 0..524287  (NB*I*HB)
    int n = idx >> 17;                              // I*HB = 131072
    int rem = idx & 131071;
    int i = rem >> 8;                               // HB = 256
    int o = rem & 255;
    int h = (n << 8) + o;
    float w = Wb[idx];
    unsigned short hi = f2bf(w);
    float fh = bf2f(hi);
    unsigned short lo = f2bf(w - fh);
    Whi[(size_t)h * II + i] = hi;
    Wlo[(size_t)h * II + i] = lo;
    if (idx < BH) {
        dS[idx] = 0.0f; vS[idx] = v0[idx]; sS[idx] = 0.0f; aS[idx] = 0.0f;
    }
}

// ---------------------------------------------------------------------------
// split_x: X fp32 [m][512] -> Xhi/Xlo bf16 [m][512] (m = b*512+t).
// (unchanged, verified in R2)
// ---------------------------------------------------------------------------
__global__ __launch_bounds__(256) void split_x(const float* __restrict__ X,
    unsigned short* __restrict__ Xhi, unsigned short* __restrict__ Xlo)
{
    size_t idx = ((size_t)blockIdx.x * 256 + threadIdx.x) << 3;   // 8 floats
    f32x4 v0 = *(const f32x4*)(X + idx);
    f32x4 v1 = *(const f32x4*)(X + idx + 4);
    union { uint4 v; int i[4]; } H, L;
    pack2(v0.x, v0.y, H.i[0], L.i[0]);
    pack2(v0.z, v0.w, H.i[1], L.i[1]);
    pack2(v1.x, v1.y, H.i[2], L.i[2]);
    pack2(v1.z, v1.w, H.i[3], L.i[3]);
    *(uint4*)(Xhi + idx) = H.v;
    *(uint4*)(Xlo + idx) = L.v;
}

// ---------------------------------------------------------------------------
// gemm8: K-loop is BYTE-IDENTICAL to the R2 harness-verified kernel
// (256x256x32, 8 waves, double-buffered 128 KiB LDS, pure global_load_lds
// staging of pre-split bf16, XOR slot swizzle, counted vmcnt(8)).
// ONLY the epilogue changed: instead of storing U (256 MB/dispatch), the
// block — which owns (batch b, h-panel 256) for ALL tl 0..255 — transposes
// acc into LDS as [h][t] fp32 (128 KiB, slot^=(h&7) swizzle) in two rounds
// and runs the serial SNN recurrence in-registers. U and scan_chunk gone.
// Numerics: verified GEMM bits + verified scan arithmetic in the same t
// order => bit-identical result.
// ---------------------------------------------------------------------------
#define GLL16(G, Lp) __builtin_amdgcn_global_load_lds(                         \
    (const __attribute__((address_space(1))) void*)(G),                        \
    (__attribute__((address_space(3))) void*)(Lp), 16, 0, 0)

#define BAR() do { asm volatile("" ::: "memory");                              \
                   __builtin_amdgcn_s_barrier();                               \
                   asm volatile("" ::: "memory"); } while (0)

// 8 global_load_lds per wave per K-tile (4 A + 4 B), 16 B/lane, lane-linear
// LDS dest, inverse-swizzled per-lane global source. K0 in elements (ushort).
#define STAGE(K0, BUFB) do {                                                   \
    _Pragma("unroll") for (int j_ = 0; j_ < 4; ++j_) {                         \
        int w8_ = (j_ << 3) + wv;                                              \
        GLL16(gA + (K0) + ((size_t)w8_ << 12), smem + (BUFB) + (w8_ << 10));   \
        GLL16(gB + (K0) + ((size_t)w8_ << 12), smem + (BUFB) + 32768 + (w8_ << 10)); \
    } } while (0)

// Load A m-frags F, F+1 (hi+lo) from buffer BUFB: 4 x ds_read_b128.
#define LDA2(F, BUFB, H0, L0, H1, L1) do {                                     \
    const char* p_ = smem + (BUFB) + aRow + ((F) << 11);                       \
    H0 = *(const bfrag8*)(p_ + sH);                                            \
    L0 = *(const bfrag8*)(p_ + sL);                                            \
    H1 = *(const bfrag8*)(p_ + 2048 + sH);                                     \
    L1 = *(const bfrag8*)(p_ + 2048 + sL);                                     \
} while (0)

// Load all 4 B n-frags (hi+lo) of this tile: 8 x ds_read_b128.
#define LOADB(BUFB) do {                                                       \
    const char* p_ = smem + (BUFB) + bRow;                                     \
    _Pragma("unroll") for (int g_ = 0; g_ < 4; ++g_) {                         \
        bh[g_] = *(const bfrag8*)(p_ + (g_ << 11) + sH);                       \
        bl[g_] = *(const bfrag8*)(p_ + (g_ << 11) + sL);                       \
    } } while (0)

#define MFMA3(AH, AL, BHG, BLG, C) do {                                        \
    C = __builtin_amdgcn_mfma_f32_16x16x32_bf16(AH, BHG, C, 0, 0, 0);          \
    C = __builtin_amdgcn_mfma_f32_16x16x32_bf16(AH, BLG, C, 0, 0, 0);          \
    C = __builtin_amdgcn_mfma_f32_16x16x32_bf16(AL, BHG, C, 0, 0, 0);          \
} while (0)

// One phase's MFMA cluster: 2 m-frags x 4 n-frags x 3 products = 24 MFMA.
#define MM2(F, H0, L0, H1, L1) do {                                            \
    __builtin_amdgcn_s_setprio(1);                                             \
    _Pragma("unroll") for (int g_ = 0; g_ < 4; ++g_) {                         \
        MFMA3(H0, L0, bh[g_], bl[g_], acc[F][g_]);                             \
        MFMA3(H1, L1, bh[g_], bl[g_], acc[(F) + 1][g_]);                       \
    }                                                                          \
    __builtin_amdgcn_s_setprio(0);                                             \
} while (0)

__global__ __launch_bounds__(512, 2) void gemm8(
    const unsigned short* __restrict__ Xhi, const unsigned short* __restrict__ Xlo,
    const unsigned short* __restrict__ Whi, const unsigned short* __restrict__ Wlo,
    const float* __restrict__ tau_n, const float* __restrict__ tau_m,
    float* __restrict__ dS, float* __restrict__ vS,
    float* __restrict__ sS, float* __restrict__ aS, int xrow0)
{
    extern __shared__ char smem[];   // 2 x { A: 32 KiB | B: 32 KiB }; reused by scan

    // bijective XCD-chunked swizzle (1024 % 8 == 0); n fastest (A-panel reuse).
    const int P = blockIdx.x;
    const int L = ((P & 7) << 7) | (P >> 3);
    const int m0 = (L >> 2) << 8;          // 256 m-tiles of 256 (m = b*TC + tl)
    const int h0 = (L & 3) << 8;           // 4 n-tiles of 256
    const int b  = L >> 2;

    const int tid = threadIdx.x;
    const int lane = tid & 63;
    const int wv = tid >> 6;               // 0..7
    const int l16 = lane & 15;
    const int q = lane >> 4;               // 0..3
    const int wm = wv >> 2, wn = wv & 3;   // wave -> (128-row, 64-col) subtile

    // swizzled read offsets (constant per lane)
    const int e = l16 & 7;
    const int sH = ((q ^ e) << 4);          // hi 16B slot
    const int sL = (((q + 4) ^ e) << 4);    // lo 16B slot
    const int aRow = ((wm << 7) + l16) << 7;            // byte, A region
    const int bRow = (((wn << 6) + l16) << 7) + 32768;  // byte, B region

    // staging source (constant per lane): inverse-swizzled slot
    const int rl = lane >> 3;                       // row within 8-row group
    const int sp = (lane & 7) ^ rl;                 // unswizzled 16B slot
    const int grow0 = (m0 << 1) + xrow0;            // global X row of tile row 0
    const unsigned short* gA = (sp < 4)
        ? (Xhi + ((size_t)(grow0 + rl) << 9) + (sp << 3))
        : (Xlo + ((size_t)(grow0 + rl) << 9) + ((sp - 4) << 3));
    const unsigned short* gB = (sp < 4)
        ? (Whi + ((size_t)(h0 + rl) << 9) + (sp << 3))
        : (Wlo + ((size_t)(h0 + rl) << 9) + ((sp - 4) << 3));

    f32x4 acc[8][4];
#pragma unroll
    for (int i = 0; i < 8; ++i)
#pragma unroll
        for (int j = 0; j < 4; ++j)
#pragma unroll
            for (int r = 0; r < 4; ++r) acc[i][j][r] = 0.0f;

    bfrag8 a0h, a0l, a1h, a1l;   // A frag set (even phases)
    bfrag8 b0h, b0l, b1h, b1l;   // A frag set (odd phases)
    bfrag8 bh[4], bl[4];         // B frags of current tile

    // prologue: stage tiles 0,1; counted wait leaves tile-1's 8 loads in flight
    STAGE(0, 0);
    STAGE(32, 65536);
    asm volatile("s_waitcnt vmcnt(8)" ::: "memory");
    __builtin_amdgcn_s_barrier();
    asm volatile("" ::: "memory");
    LDA2(0, 0, a0h, a0l, a1h, a1l);

    // 16 K-tiles, 2 per iteration (even=buf0, odd=buf1). Per tile 4 phases.
    // (BYTE-IDENTICAL to R2 verified loop.)
#pragma unroll 1
    for (int tt = 0; tt < 16; tt += 2) {
        const int k2 = (tt << 5) + 64;   // k0 of tile tt+2 (elements)
        // ---------------- even tile (buf 0) ----------------
        LOADB(0);
        LDA2(2, 0, b0h, b0l, b1h, b1l);
        MM2(0, a0h, a0l, a1h, a1l);
        BAR();
        LDA2(4, 0, a0h, a0l, a1h, a1l);
        MM2(2, b0h, b0l, b1h, b1l);
        BAR();
        LDA2(6, 0, b0h, b0l, b1h, b1l);
        MM2(4, a0h, a0l, a1h, a1l);
        asm volatile("s_waitcnt lgkmcnt(0)" ::: "memory");
        BAR();
        if (tt < 14) {
            STAGE(k2, 0);                             // tile tt+2 -> buf0
            MM2(6, b0h, b0l, b1h, b1l);
            asm volatile("s_waitcnt vmcnt(8)" ::: "memory");   // tt+1 staged
        } else {
            MM2(6, b0h, b0l, b1h, b1l);
            asm volatile("s_waitcnt vmcnt(0)" ::: "memory");   // tile 15 staged
        }
        LDA2(0, 65536, a0h, a0l, a1h, a1l);           // tile tt+1 frags {0,1}
        BAR();
        // ---------------- odd tile (buf 1) ----------------
        LOADB(65536);
        LDA2(2, 65536, b0h, b0l, b1h, b1l);
        MM2(0, a0h, a0l, a1h, a1l);
        BAR();
        LDA2(4, 65536, a0h, a0l, a1h, a1l);
        MM2(2, b0h, b0l, b1h, b1l);
        BAR();
        LDA2(6, 65536, b0h, b0l, b1h, b1l);
        MM2(4, a0h, a0l, a1h, a1l);
        asm volatile("s_waitcnt lgkmcnt(0)" ::: "memory");
        BAR();
        if (tt < 13) {
            STAGE(k2 + 32, 65536);                    // tile tt+3 -> buf1
            MM2(6, b0h, b0l, b1h, b1l);
            asm volatile("s_waitcnt vmcnt(8)" ::: "memory");   // tt+2 staged
            LDA2(0, 0, a0h, a0l, a1h, a1l);           // tile tt+2 frags {0,1}
        } else {
            MM2(6, b0h, b0l, b1h, b1l);               // tile 15: done
        }
        BAR();
    }

    // ---- fused scan epilogue (the ONLY change vs the verified R2 kernel) ----
    // acc[f][g][rr] holds U at tl = wm*128 + f*16 + q*4 + rr,
    //                         h  = h0 + wn*64 + g*16 + l16.
    // Round R: waves wm==R write [h][t] fp32 (h row = 512 B = 32 16B-slots,
    // slot swizzled ^(h&7)); 256 scanner threads (tid<256) run the serial SNN
    // recurrence t ascending (t = s4*4 + r within round, rounds in order).
    float dd = 0.f, vv = 0.f, ssp = 0.f, aa = 0.f, beta = 0.f, alpha = 0.f, ob = 0.f, oa = 0.f;
    if (tid < 256) {
        const int hg = h0 + tid;
        const int sidx = b * HH + hg;
        beta  = 1.0f / (1.0f + __expf(-tau_n[hg]));
        alpha = 1.0f / (1.0f + __expf(-tau_m[hg]));
        ob = 1.0f - beta; oa = 1.0f - alpha;
        dd = dS[sidx]; vv = vS[sidx]; ssp = sS[sidx]; aa = aS[sidx];
    }
    const float lv = (xrow0 >= TT / 2) ? 1.0f : 0.0f;   // mask: global t >= 256

#pragma unroll
    for (int R = 0; R < 2; ++R) {
        if (wm == R) {
#pragma unroll
            for (int f = 0; f < 8; ++f)
#pragma unroll
                for (int g = 0; g < 4; ++g) {
                    const int hloc = (wn << 6) + (g << 4) + l16;
                    const int slot = (f << 2) + q;
                    *(f32x4*)(smem + (hloc << 9) + ((slot ^ (hloc & 7)) << 4)) = acc[f][g];
                }
        }
        __syncthreads();
        if (tid < 256) {
            const char* bp = smem + (tid << 9);
            const int eh = tid & 7;
#pragma unroll 8
            for (int s4 = 0; s4 < 32; ++s4) {
                f32x4 u4 = *(const f32x4*)(bp + ((s4 ^ eh) << 4));
#pragma unroll
                for (int r = 0; r < 4; ++r) {
                    dd = beta * dd + ob * u4[r];
                    vv = alpha * vv + oa * dd - ssp;   // prev s; V_TH=1
                    ssp = (vv > 1.0f) ? 1.0f : 0.0f;
                    aa += lv * ssp;
                }
            }
        }
        __syncthreads();
    }
    if (tid < 256) {
        const int sidx = b * HH + h0 + tid;
        dS[sidx] = dd; vS[sidx] = vv; sS[sidx] = ssp; aS[sidx] = aa;
    }
}

// ---------------------------------------------------------------------------
// out[b][o] = sum_h acc[b][h] * W_out[h][o] + b_out[o]   (unchanged)
// ---------------------------------------------------------------------------
__global__ __launch_bounds__(256) void out_gemm(const float* __restrict__ acc,
    const float* __restrict__ Wout, const float* __restrict__ bout,
    float* __restrict__ out)
{
    __shared__ float a_s[HH];
    __shared__ float partial[OO];
    int b = blockIdx.x;
    int o = threadIdx.x & (OO - 1);
    int half = threadIdx.x >> 7;
    for (int i = threadIdx.x; i < HH; i += 256) a_s[i] = acc[b * HH + i];
    __syncthreads();
    float sum = half ? 0.0f : bout[o];
    const float* Wp = Wout + (size_t)half * 512 * OO + o;
    const float* ap = a_s + half * 512;
#pragma unroll 8
    for (int h = 0; h < 512; ++h) sum = fmaf(ap[h], Wp[(size_t)h * OO], sum);
    if (half) partial[o] = sum;
    __syncthreads();
    if (!half) out[b * OO + o] = sum + partial[o];
}

// ---------------------------------------------------------------------------
extern "C" void kernel_launch(void* const* d_in, const int* in_sizes, int n_in,
                              void* d_out, int out_size, void* d_ws, size_t ws_size,
                              hipStream_t stream) {
    const float* x     = (const float*)d_in[0];
    const float* v0    = (const float*)d_in[1];
    const float* Wb    = (const float*)d_in[2];
    const float* tau_n = (const float*)d_in[3];
    const float* tau_m = (const float*)d_in[4];
    const float* Wout  = (const float*)d_in[5];
    const float* bout  = (const float*)d_in[6];
    float* out = (float*)d_out;

    // workspace (262 MiB used; same offsets as verified R2 layout):
    //  Whi 1M | Wlo 1M | dS 1M | vS 1M | sS 1M | aS 1M | Xhi 128M | Xlo 128M
    char* ws = (char*)d_ws;
    unsigned short* Whi = (unsigned short*)(ws);
    unsigned short* Wlo = (unsigned short*)(ws + (1ll << 20));
    float* dS = (float*)(ws + (2ll << 20));
    float* vS = (float*)(ws + (3ll << 20));
    float* sS = (float*)(ws + (4ll << 20));
    float* aS = (float*)(ws + (5ll << 20));
    unsigned short* Xhi = (unsigned short*)(ws + (6ll << 20));
    unsigned short* Xlo = (unsigned short*)(ws + (134ll << 20));

    // 128 KiB dynamic LDS (> 64 KiB default cap)
    hipFuncSetAttribute((const void*)gemm8,
                        hipFuncAttributeMaxDynamicSharedMemorySize, 131072);

    setup_k<<<2048, 256, 0, stream>>>(Wb, v0, Whi, Wlo, dS, vS, sS, aS);
    split_x<<<32768, 256, 0, stream>>>(x, Xhi, Xlo);

    for (int t0 = 0; t0 < TT; t0 += TC) {
        gemm8<<<1024, 512, 131072, stream>>>(Xhi, Xlo, Whi, Wlo, tau_n, tau_m,
                                             dS, vS, sS, aS, t0);
    }
    out_gemm<<<BSZ, 256, 0, stream>>>(aS, Wout, bout, out);
}